// Round 7
// baseline (612.226 us; speedup 1.0000x reference)
//
#include <hip/hip_runtime.h>
#include <hip/hip_bf16.h>

typedef unsigned short u16;

#define M_ROWS 8192
#define N_ROWS 16384
#define KDIM   512
#define BM     128
#define BN     128
#define BK     32
#define NCHUNKS 16
#define NPER   (N_ROWS / NCHUNKS)   /* 1024 */
#define NT_CNT (NPER / BN)          /* 8 */
#define KC_CNT (KDIM / BK)          /* 16 */
#define TOPK   9

typedef __attribute__((ext_vector_type(8)))  short bf16x8;
typedef __attribute__((ext_vector_type(16))) float f32x16;

__device__ __forceinline__ void gload_lds16(const void* g, void* l) {
  __builtin_amdgcn_global_load_lds(
      (const __attribute__((address_space(1))) void*)g,
      (__attribute__((address_space(3))) void*)l,
      16, 0, 0);
}

__device__ __forceinline__ u16 f2bf(float x) {
  union { float f; unsigned u; } c; c.f = x;
  unsigned u = c.u;
  u += 0x7fffu + ((u >> 16) & 1u);   // RNE; inputs finite randn
  return (u16)(u >> 16);
}

__device__ __forceinline__ void topk_update(float v, float best[TOPK]) {
  if (v < best[TOPK - 1]) {
    #pragma unroll
    for (int i = 0; i < TOPK; ++i) {
      float b = best[i];
      best[i] = fminf(b, v);
      v = fmaxf(b, v);
    }
  }
}

// ---- Kernel 1: fp32 -> bf16 convert + fp32 row norms; mb norms scattered into
//      MFMA-C-layout permuted order so the GEMM epilogue reads them as broadcasts.
__global__ __launch_bounds__(256) void prep_kernel(
    const float* __restrict__ fv, const float* __restrict__ mb,
    u16* __restrict__ fvb, u16* __restrict__ mbb,
    float* __restrict__ nf, float* __restrict__ nm_perm)
{
  int idx = blockIdx.x * 4 + (threadIdx.x >> 6);   // one wave per row
  int l = threadIdx.x & 63;
  const float* src; u16* dst;
  if (idx < M_ROWS) {
    src = fv + (size_t)idx * KDIM; dst = fvb + (size_t)idx * KDIM;
  } else {
    int r = idx - M_ROWS;
    src = mb + (size_t)r * KDIM; dst = mbb + (size_t)r * KDIM;
  }
  float4 x0 = ((const float4*)src)[2 * l];
  float4 x1 = ((const float4*)src)[2 * l + 1];
  float s = x0.x * x0.x + x0.y * x0.y + x0.z * x0.z + x0.w * x0.w
          + x1.x * x1.x + x1.y * x1.y + x1.z * x1.z + x1.w * x1.w;
  uint4 o;
  o.x = (unsigned)f2bf(x0.x) | ((unsigned)f2bf(x0.y) << 16);
  o.y = (unsigned)f2bf(x0.z) | ((unsigned)f2bf(x0.w) << 16);
  o.z = (unsigned)f2bf(x1.x) | ((unsigned)f2bf(x1.y) << 16);
  o.w = (unsigned)f2bf(x1.z) | ((unsigned)f2bf(x1.w) << 16);
  ((uint4*)dst)[l] = o;
  #pragma unroll
  for (int off = 32; off > 0; off >>= 1) s += __shfl_down(s, off, 64);
  if (l == 0) {
    if (idx < M_ROWS) {
      nf[idx] = s;
    } else {
      // 32x32 C/D: within-tile row w5 = (r&3) + 8*(r>>2) + 4*h  ->  [tile][h][r]
      int n  = idx - M_ROWS;
      int ig = n >> 5;            // global 32-row tile index (512 tiles)
      int w5 = n & 31;
      int h  = (w5 >> 2) & 1;
      int r  = (w5 & 3) | ((w5 >> 3) << 2);
      nm_perm[(ig * 2 + h) * 16 + r] = s;
    }
  }
}

// ---- Kernel 2: bf16 32x32x16 MFMA GEMM, 2x2 wave tile, BK=32 dbuf, slim regs ----
// R6 post-mortem: binder was combined VGPR+AGPR (124+64=188 -> 2 waves/SIMD, Occ
// 22% across R4/R5/R6 regardless of grid/LDS). This round: arch-VGPR diet
// (no v[] staging array; rare insert branch recomputes) + launch_bounds(256,3)
// to target combined <=170 -> 3 waves/SIMD; BK=32 dbuf = 32 KB LDS so 3 blocks/CU
// fit; NCHUNKS=16 -> 1024 blocks so 3/CU are schedulable.
// Swizzle (64 B rows, 4 chunks of 16 B): phys chunk = logical ^ (row&3);
// 8 lanes per 4-bank group per frag read -> conflict-free minimum.
__global__ __launch_bounds__(256, 3) void gemm_topk_kernel(
    const u16* __restrict__ fvb, const u16* __restrict__ mbb,
    const float* __restrict__ nm_perm, float* __restrict__ partial)
{
  __shared__ __align__(16) u16 As[2][BM * BK];  // fv tiles, 2 x 8 KB
  __shared__ __align__(16) u16 Bs[2][BN * BK];  // mb tiles, 2 x 8 KB

  const int t   = threadIdx.x;
  const int l   = t & 63;
  const int w   = t >> 6;
  const int wm  = w & 1;         // m half (cols)
  const int wn  = w >> 1;        // n half (rows)
  const int h   = l >> 5;        // half-wave
  const int c31 = l & 31;
  const int cx  = c31 & 3;       // frag-read row&3

  const int m0    = blockIdx.x * BM;
  const int ncoff = blockIdx.y * NPER;

  // staging: 2 gloads per operand per wave; lane covers row base+(l>>2), 16 rows/gload
  const int srow_lo = l >> 2;                    // 0..15
  const int sc      = ((l & 3) ^ (srow_lo & 3)) * 8;  // swizzled source k-offset (u16)

  float best[2][TOPK];
  float T[2];
  #pragma unroll
  for (int j = 0; j < 2; ++j) {
    T[j] = 3.4e38f;
    #pragma unroll
    for (int i = 0; i < TOPK; ++i) best[j][i] = 3.4e38f;
  }

  // preload tile (nt=0, kc=0) into buffer 0
  {
    #pragma unroll
    for (int g = 0; g < 2; ++g) {
      gload_lds16(fvb + (size_t)(m0 + w * 32 + g * 16 + srow_lo) * KDIM + sc,
                  &As[0][(w * 32 + g * 16) * BK]);
      gload_lds16(mbb + (size_t)(ncoff + w * 32 + g * 16 + srow_lo) * KDIM + sc,
                  &Bs[0][(w * 32 + g * 16) * BK]);
    }
  }

  for (int nt = 0; nt < NT_CNT; ++nt) {
    const int nbase = ncoff + nt * BN;
    f32x16 acc[2][2];
    #pragma unroll
    for (int i = 0; i < 2; ++i)
      #pragma unroll
      for (int j = 0; j < 2; ++j)
        #pragma unroll
        for (int r = 0; r < 16; ++r) acc[i][j][r] = 0.0f;

    for (int kc = 0; kc < KC_CNT; ++kc) {
      const int cur = kc & 1;
      __syncthreads();   // buf[cur] staged (loads issued one kc ago drained here)
      if (kc < KC_CNT - 1) {
        const int kb = (kc + 1) * BK + sc;
        #pragma unroll
        for (int g = 0; g < 2; ++g) {
          gload_lds16(fvb + (size_t)(m0 + w * 32 + g * 16 + srow_lo) * KDIM + kb,
                      &As[cur ^ 1][(w * 32 + g * 16) * BK]);
          gload_lds16(mbb + (size_t)(nbase + w * 32 + g * 16 + srow_lo) * KDIM + kb,
                      &Bs[cur ^ 1][(w * 32 + g * 16) * BK]);
        }
      } else if (nt + 1 < NT_CNT) {
        #pragma unroll
        for (int g = 0; g < 2; ++g) {
          gload_lds16(fvb + (size_t)(m0 + w * 32 + g * 16 + srow_lo) * KDIM + sc,
                      &As[cur ^ 1][(w * 32 + g * 16) * BK]);
          gload_lds16(mbb + (size_t)(nbase + BN + w * 32 + g * 16 + srow_lo) * KDIM + sc,
                      &Bs[cur ^ 1][(w * 32 + g * 16) * BK]);
        }
      }
      // compute on buf[cur]: 2 kk steps (K=16 each)
      #pragma unroll
      for (int kk = 0; kk < 2; ++kk) {
        const int ch = ((kk * 2 + h) ^ cx) * 8;              // swizzled chunk (u16)
        bf16x8 fvf0 = *(const bf16x8*)&As[cur][(wm * 64 + c31) * BK + ch];
        bf16x8 fvf1 = *(const bf16x8*)&As[cur][(wm * 64 + 32 + c31) * BK + ch];
        bf16x8 mbf0 = *(const bf16x8*)&Bs[cur][(wn * 64 + c31) * BK + ch];
        bf16x8 mbf1 = *(const bf16x8*)&Bs[cur][(wn * 64 + 32 + c31) * BK + ch];
        acc[0][0] = __builtin_amdgcn_mfma_f32_32x32x16_bf16(mbf0, fvf0, acc[0][0], 0, 0, 0);
        acc[0][1] = __builtin_amdgcn_mfma_f32_32x32x16_bf16(mbf0, fvf1, acc[0][1], 0, 0, 0);
        acc[1][0] = __builtin_amdgcn_mfma_f32_32x32x16_bf16(mbf1, fvf0, acc[1][0], 0, 0, 0);
        acc[1][1] = __builtin_amdgcn_mfma_f32_32x32x16_bf16(mbf1, fvf1, acc[1][1], 0, 0, 0);
      }
    }

    // ---- slim register epilogue: bmin direct from acc; rare branch recomputes ----
    #pragma unroll
    for (int j = 0; j < 2; ++j) {
      float bmin = 3.4e38f;
      #pragma unroll
      for (int i = 0; i < 2; ++i) {
        const float4* np =
            (const float4*)&nm_perm[(((nbase >> 5) + wn * 2 + i) * 2 + h) * 16];
        #pragma unroll
        for (int rr = 0; rr < 4; ++rr) {
          float4 q = np[rr];
          bmin = fminf(bmin, fmaf(-2.0f, acc[i][j][rr * 4 + 0], q.x));
          bmin = fminf(bmin, fmaf(-2.0f, acc[i][j][rr * 4 + 1], q.y));
          bmin = fminf(bmin, fmaf(-2.0f, acc[i][j][rr * 4 + 2], q.z));
          bmin = fminf(bmin, fmaf(-2.0f, acc[i][j][rr * 4 + 3], q.w));
        }
      }
      if (bmin < T[j]) {
        #pragma unroll
        for (int i = 0; i < 2; ++i) {
          const float4* np =
              (const float4*)&nm_perm[(((nbase >> 5) + wn * 2 + i) * 2 + h) * 16];
          #pragma unroll
          for (int rr = 0; rr < 4; ++rr) {
            float4 q = np[rr];
            topk_update(fmaf(-2.0f, acc[i][j][rr * 4 + 0], q.x), best[j]);
            topk_update(fmaf(-2.0f, acc[i][j][rr * 4 + 1], q.y), best[j]);
            topk_update(fmaf(-2.0f, acc[i][j][rr * 4 + 2], q.z), best[j]);
            topk_update(fmaf(-2.0f, acc[i][j][rr * 4 + 3], q.w), best[j]);
          }
        }
      }
      float th = best[j][TOPK - 1];
      T[j] = fminf(th, __shfl_xor(th, 32, 64));
    }
  }

  // merge the h-pair sharing each m-col (snapshot partner list, then insert)
  #pragma unroll
  for (int j = 0; j < 2; ++j) {
    float tmp[TOPK];
    #pragma unroll
    for (int s = 0; s < TOPK; ++s) tmp[s] = __shfl_xor(best[j][s], 32, 64);
    #pragma unroll
    for (int s = 0; s < TOPK; ++s) topk_update(tmp[s], best[j]);
  }
  // 32 lists per row: (blockIdx.y, wn); h=0 writes 5, h=1 writes 4
  #pragma unroll
  for (int j = 0; j < 2; ++j) {
    int m = m0 + wm * 64 + j * 32 + c31;
    size_t base = ((size_t)(blockIdx.y * 2 + wn) * M_ROWS + m) * TOPK;
    if (h == 0) {
      #pragma unroll
      for (int s = 0; s < 5; ++s) partial[base + s] = best[j][s];
    } else {
      #pragma unroll
      for (int s = 5; s < TOPK; ++s) partial[base + s] = best[j][s];
    }
  }
}

// ---- Kernel 3 (fused merge+img): one block per image; merge 32 lists/row,
//      sqrt, pixel scores, per-image first-max argmax, softmax image score.
__global__ __launch_bounds__(256) void scoring_kernel(
    const float* __restrict__ partial, const float* __restrict__ nf,
    const int* __restrict__ bptr, float* __restrict__ out_pix,
    float* __restrict__ out_img)
{
  const int img = blockIdx.x, t = threadIdx.x;
  __shared__ float sd[256][TOPK];
  __shared__ float sv[256];
  __shared__ int   si[256];

  float bv = -1.0f; int bi = 0;
  float bd[TOPK];
  #pragma unroll
  for (int i = 0; i < TOPK; ++i) bd[i] = 0.0f;

  for (int rr = 0; rr < 4; ++rr) {             // ascending rows -> first-max kept
    int row = img * 1024 + rr * 256 + t;
    float best[TOPK];
    #pragma unroll
    for (int i = 0; i < TOPK; ++i) best[i] = 3.4e38f;
    for (int s = 0; s < 2 * NCHUNKS; ++s) {
      const float* p = &partial[((size_t)s * M_ROWS + row) * TOPK];
      #pragma unroll
      for (int i = 0; i < TOPK; ++i) topk_update(p[i], best);
    }
    float nfr = nf[row];
    float d[TOPK];
    #pragma unroll
    for (int i = 0; i < TOPK; ++i) d[i] = sqrtf(fmaxf(best[i] + nfr, 0.0f));
    out_pix[row] = d[0];
    if (d[0] > bv) {
      bv = d[0]; bi = row;
      #pragma unroll
      for (int i = 0; i < TOPK; ++i) bd[i] = d[i];
    }
  }
  sv[t] = bv; si[t] = bi;
  #pragma unroll
  for (int i = 0; i < TOPK; ++i) sd[t][i] = bd[i];
  __syncthreads();
  for (int off = 128; off > 0; off >>= 1) {
    if (t < off) {
      float v2 = sv[t + off]; int i2 = si[t + off];
      if (v2 > sv[t] || (v2 == sv[t] && i2 < si[t])) { sv[t] = v2; si[t] = i2; }
    }
    __syncthreads();
  }
  if (t == 0) {
    int wt = si[0] & 255;          // row = img*1024 + rr*256 + t  ->  t = row & 255
    int b = bptr[0];
    float s0 = sd[wt][0];
    float score = s0;
    if (b > 1) {
      int bb = b < TOPK ? b : TOPK;
      float mx = s0;
      for (int i = 1; i < bb; ++i) mx = fmaxf(mx, sd[wt][i]);
      float den = 0.0f;
      for (int i = 0; i < bb; ++i) den += expf(sd[wt][i] - mx);
      score = s0 * (1.0f - expf(s0 - mx) / den);
    }
    out_img[img] = score;
  }
}

extern "C" void kernel_launch(void* const* d_in, const int* in_sizes, int n_in,
                              void* d_out, int out_size, void* d_ws, size_t ws_size,
                              hipStream_t stream) {
  const float* fv   = (const float*)d_in[0];
  const float* mb   = (const float*)d_in[1];
  const int*   bptr = (const int*)d_in[2];
  float* out = (float*)d_out;

  char* w = (char*)d_ws;
  u16*   fvb     = (u16*)w;                        // 8388608 B
  u16*   mbb     = (u16*)(w + 8388608);            // 16777216 B
  float* nf      = (float*)(w + 25165824);         // 32768 B
  float* nm_perm = (float*)(w + 25198592);         // 65536 B
  float* partial = (float*)(w + 25264128);         // 32*8192*9*4 = 9437184 B (end ~34.7 MB)

  hipLaunchKernelGGL(prep_kernel, dim3((M_ROWS + N_ROWS) / 4), dim3(256), 0, stream,
                     fv, mb, fvb, mbb, nf, nm_perm);
  hipLaunchKernelGGL(gemm_topk_kernel, dim3(M_ROWS / BM, NCHUNKS), dim3(256), 0, stream,
                     fvb, mbb, nm_perm, partial);
  hipLaunchKernelGGL(scoring_kernel, dim3(8), dim3(256), 0, stream,
                     partial, nf, bptr, out, out + M_ROWS);
}

// Round 8
// 537.517 us; speedup vs baseline: 1.1390x; 1.1390x over previous
//
#include <hip/hip_runtime.h>
#include <hip/hip_bf16.h>
#include <hip/hip_fp8.h>

typedef unsigned short u16;
typedef unsigned char  u8;

#define M_ROWS 8192
#define N_ROWS 16384
#define KDIM   512
#define BM     128
#define BN     128
#define BK     64
#define NCHUNKS 8
#define NPER   (N_ROWS / NCHUNKS)   /* 2048 */
#define NT_CNT (NPER / BN)          /* 16 */
#define KC_CNT (KDIM / BK)          /* 8 */
#define TOPK   9

typedef __attribute__((ext_vector_type(16))) float f32x16;

__device__ __forceinline__ void gload_lds4(const void* g, void* l) {
  __builtin_amdgcn_global_load_lds(
      (const __attribute__((address_space(1))) void*)g,
      (__attribute__((address_space(3))) void*)l,
      4, 0, 0);
}

__device__ __forceinline__ u8 f2fp8(float x) {
  __hip_fp8_e4m3 q(x);               // OCP e4m3fn on gfx950, RNE+sat
  return (u8)q.__x;
}

__device__ __forceinline__ void topk_update(float v, float best[TOPK]) {
  if (v < best[TOPK - 1]) {
    #pragma unroll
    for (int i = 0; i < TOPK; ++i) {
      float b = best[i];
      best[i] = fminf(b, v);
      v = fmaxf(b, v);
    }
  }
}

// ---- Kernel 1: fp32 -> fp8(e4m3) convert + EXACT fp32 row norms; mb norms in
//      MFMA-C-layout permuted order (exact norms + fp8 dot approximates ref sq).
__global__ __launch_bounds__(256) void prep_kernel(
    const float* __restrict__ fv, const float* __restrict__ mb,
    u8* __restrict__ fvб_unused, u8* __restrict__ mbb_unused,  // kept for symmetry
    u8* __restrict__ fvq, u8* __restrict__ mbq,
    float* __restrict__ nf, float* __restrict__ nm_perm)
{
  int idx = blockIdx.x * 4 + (threadIdx.x >> 6);   // one wave per row
  int l = threadIdx.x & 63;
  const float* src; u8* dst;
  if (idx < M_ROWS) {
    src = fv + (size_t)idx * KDIM; dst = fvq + (size_t)idx * KDIM;
  } else {
    int r = idx - M_ROWS;
    src = mb + (size_t)r * KDIM; dst = mbq + (size_t)r * KDIM;
  }
  float4 x0 = ((const float4*)src)[2 * l];
  float4 x1 = ((const float4*)src)[2 * l + 1];
  float s = x0.x * x0.x + x0.y * x0.y + x0.z * x0.z + x0.w * x0.w
          + x1.x * x1.x + x1.y * x1.y + x1.z * x1.z + x1.w * x1.w;
  unsigned lo = (unsigned)f2fp8(x0.x) | ((unsigned)f2fp8(x0.y) << 8)
              | ((unsigned)f2fp8(x0.z) << 16) | ((unsigned)f2fp8(x0.w) << 24);
  unsigned hi = (unsigned)f2fp8(x1.x) | ((unsigned)f2fp8(x1.y) << 8)
              | ((unsigned)f2fp8(x1.z) << 16) | ((unsigned)f2fp8(x1.w) << 24);
  uint2 o; o.x = lo; o.y = hi;
  ((uint2*)dst)[l] = o;                            // 8 B/lane, row = 512 B
  #pragma unroll
  for (int off = 32; off > 0; off >>= 1) s += __shfl_down(s, off, 64);
  if (l == 0) {
    if (idx < M_ROWS) {
      nf[idx] = s;
    } else {
      // 32x32 C/D: within-tile row w5 = (r&3) + 8*(r>>2) + 4*h  ->  [tile][h][r]
      int n  = idx - M_ROWS;
      int ig = n >> 5;
      int w5 = n & 31;
      int h  = (w5 >> 2) & 1;
      int r  = (w5 & 3) | ((w5 >> 3) << 2);
      nm_perm[(ig * 2 + h) * 16 + r] = s;
    }
  }
}

// ---- Kernel 2: fp8 32x32x16 MFMA GEMM, 2x2 wave tile, BK=64 dbuf, reg top-9 ----
// R7 post-mortem: min-waves caps spill (twice) -> plain launch_bounds(256); the
// 2-waves/SIMD regime is accepted and the LDS port (R6's binder, ~120us) is
// halved instead by fp8: frag reads ds_read_b64, tiles 8 KB, staging width-4
// global_load_lds with per-dword octet swizzle.
// LDS layout: row = 64 B (BK fp8); phys octet p of row r holds logical octet
// p^(r&7) (within-octet dword order kept). Staging: lane l of gload g writes
// phys dword l&15 of row g*4+(l>>4) (hw: uniform base + lane*4); it FETCHES
// logical dword ((d>>1)^(r&7))*2+(d&1) of the source row -- coalesced within
// each 64 B line. Frag b64 reads: bank-pairs get 4 lanes each = minimum.
__global__ __launch_bounds__(256) void gemm_topk_kernel(
    const u8* __restrict__ fvq, const u8* __restrict__ mbq,
    const float* __restrict__ nm_perm, float* __restrict__ partial)
{
  __shared__ __align__(16) u8 As[2][BM * BK];   // fv tiles, 2 x 8 KB
  __shared__ __align__(16) u8 Bs[2][BN * BK];   // mb tiles, 2 x 8 KB

  const int t   = threadIdx.x;
  const int l   = t & 63;
  const int w   = t >> 6;
  const int wm  = w & 1;         // m half (cols)
  const int wn  = w >> 1;        // n half (rows)
  const int h   = l >> 5;        // half-wave
  const int c31 = l & 31;
  const int cx7 = c31 & 7;       // frag row & 7

  const int m0    = blockIdx.x * BM;
  const int ncoff = blockIdx.y * NPER;

  // staging per-lane constants
  const int d  = l & 15;         // dword within 64 B row
  const int rg = l >> 4;         // row within gload (4 rows / gload)
  int swl[8];                    // source dword index per gload (kc-invariant)
  #pragma unroll
  for (int g = 0; g < 8; ++g) {
    int r7 = (g * 4 + rg) & 7;
    swl[g] = (((d >> 1) ^ r7) << 1) | (d & 1);
  }

  float best[2][TOPK];
  float T[2];
  #pragma unroll
  for (int j = 0; j < 2; ++j) {
    T[j] = 3.4e38f;
    #pragma unroll
    for (int i = 0; i < TOPK; ++i) best[j][i] = 3.4e38f;
  }

  // preload tile (nt=0, kc=0) into buffer 0
  #pragma unroll
  for (int g = 0; g < 8; ++g) {
    int row = w * 32 + g * 4 + rg;
    gload_lds4(fvq + (size_t)(m0 + row) * KDIM + swl[g] * 4,
               &As[0][(w * 32 + g * 4) * BK]);
    gload_lds4(mbq + (size_t)(ncoff + row) * KDIM + swl[g] * 4,
               &Bs[0][(w * 32 + g * 4) * BK]);
  }

  for (int nt = 0; nt < NT_CNT; ++nt) {
    const int nbase = ncoff + nt * BN;
    f32x16 acc[2][2];
    #pragma unroll
    for (int i = 0; i < 2; ++i)
      #pragma unroll
      for (int j = 0; j < 2; ++j)
        #pragma unroll
        for (int r = 0; r < 16; ++r) acc[i][j][r] = 0.0f;

    for (int kc = 0; kc < KC_CNT; ++kc) {
      const int cur = kc & 1;
      __syncthreads();   // buf[cur] staged (loads issued one kc ago drained here)
      if (kc < KC_CNT - 1) {
        const int kb = (kc + 1) * BK;
        #pragma unroll
        for (int g = 0; g < 8; ++g) {
          int row = w * 32 + g * 4 + rg;
          gload_lds4(fvq + (size_t)(m0 + row) * KDIM + kb + swl[g] * 4,
                     &As[cur ^ 1][(w * 32 + g * 4) * BK]);
          gload_lds4(mbq + (size_t)(nbase + row) * KDIM + kb + swl[g] * 4,
                     &Bs[cur ^ 1][(w * 32 + g * 4) * BK]);
        }
      } else if (nt + 1 < NT_CNT) {
        #pragma unroll
        for (int g = 0; g < 8; ++g) {
          int row = w * 32 + g * 4 + rg;
          gload_lds4(fvq + (size_t)(m0 + row) * KDIM + swl[g] * 4,
                     &As[cur ^ 1][(w * 32 + g * 4) * BK]);
          gload_lds4(mbq + (size_t)(nbase + BN + row) * KDIM + swl[g] * 4,
                     &Bs[cur ^ 1][(w * 32 + g * 4) * BK]);
        }
      }
      // compute on buf[cur]: 4 kk steps (K=16 each), b64 frags
      const u8* a0 = &As[cur][(wm * 64 + c31) * BK];
      const u8* a1 = &As[cur][(wm * 64 + 32 + c31) * BK];
      const u8* b0 = &Bs[cur][(wn * 64 + c31) * BK];
      const u8* b1 = &Bs[cur][(wn * 64 + 32 + c31) * BK];
      #pragma unroll
      for (int kk = 0; kk < 4; ++kk) {
        const int ch = ((kk * 2 + h) ^ cx7) * 8;   // swizzled octet byte offset
        long fvf0 = *(const long*)&a0[ch];
        long fvf1 = *(const long*)&a1[ch];
        long mbf0 = *(const long*)&b0[ch];
        long mbf1 = *(const long*)&b1[ch];
        acc[0][0] = __builtin_amdgcn_mfma_f32_32x32x16_fp8_fp8(mbf0, fvf0, acc[0][0], 0, 0, 0);
        acc[0][1] = __builtin_amdgcn_mfma_f32_32x32x16_fp8_fp8(mbf0, fvf1, acc[0][1], 0, 0, 0);
        acc[1][0] = __builtin_amdgcn_mfma_f32_32x32x16_fp8_fp8(mbf1, fvf0, acc[1][0], 0, 0, 0);
        acc[1][1] = __builtin_amdgcn_mfma_f32_32x32x16_fp8_fp8(mbf1, fvf1, acc[1][1], 0, 0, 0);
      }
    }

    // ---- register epilogue: bmin direct from acc; rare branch recomputes ----
    #pragma unroll
    for (int j = 0; j < 2; ++j) {
      float bmin = 3.4e38f;
      #pragma unroll
      for (int i = 0; i < 2; ++i) {
        const float4* np =
            (const float4*)&nm_perm[(((nbase >> 5) + wn * 2 + i) * 2 + h) * 16];
        #pragma unroll
        for (int rr = 0; rr < 4; ++rr) {
          float4 q = np[rr];
          bmin = fminf(bmin, fmaf(-2.0f, acc[i][j][rr * 4 + 0], q.x));
          bmin = fminf(bmin, fmaf(-2.0f, acc[i][j][rr * 4 + 1], q.y));
          bmin = fminf(bmin, fmaf(-2.0f, acc[i][j][rr * 4 + 2], q.z));
          bmin = fminf(bmin, fmaf(-2.0f, acc[i][j][rr * 4 + 3], q.w));
        }
      }
      if (bmin < T[j]) {
        #pragma unroll
        for (int i = 0; i < 2; ++i) {
          const float4* np =
              (const float4*)&nm_perm[(((nbase >> 5) + wn * 2 + i) * 2 + h) * 16];
          #pragma unroll
          for (int rr = 0; rr < 4; ++rr) {
            float4 q = np[rr];
            topk_update(fmaf(-2.0f, acc[i][j][rr * 4 + 0], q.x), best[j]);
            topk_update(fmaf(-2.0f, acc[i][j][rr * 4 + 1], q.y), best[j]);
            topk_update(fmaf(-2.0f, acc[i][j][rr * 4 + 2], q.z), best[j]);
            topk_update(fmaf(-2.0f, acc[i][j][rr * 4 + 3], q.w), best[j]);
          }
        }
      }
      float th = best[j][TOPK - 1];
      T[j] = fminf(th, __shfl_xor(th, 32, 64));
    }
  }

  // merge the h-pair sharing each m-col (snapshot partner list, then insert)
  #pragma unroll
  for (int j = 0; j < 2; ++j) {
    float tmp[TOPK];
    #pragma unroll
    for (int s = 0; s < TOPK; ++s) tmp[s] = __shfl_xor(best[j][s], 32, 64);
    #pragma unroll
    for (int s = 0; s < TOPK; ++s) topk_update(tmp[s], best[j]);
  }
  // 16 lists per row: (blockIdx.y, wn); h=0 writes 5, h=1 writes 4
  #pragma unroll
  for (int j = 0; j < 2; ++j) {
    int m = m0 + wm * 64 + j * 32 + c31;
    size_t base = ((size_t)(blockIdx.y * 2 + wn) * M_ROWS + m) * TOPK;
    if (h == 0) {
      #pragma unroll
      for (int s = 0; s < 5; ++s) partial[base + s] = best[j][s];
    } else {
      #pragma unroll
      for (int s = 5; s < TOPK; ++s) partial[base + s] = best[j][s];
    }
  }
}

// ---- Kernel 3 (fused merge+img): one block per image; merge 16 lists/row,
//      sqrt, pixel scores, per-image first-max argmax, softmax image score.
__global__ __launch_bounds__(256) void scoring_kernel(
    const float* __restrict__ partial, const float* __restrict__ nf,
    const int* __restrict__ bptr, float* __restrict__ out_pix,
    float* __restrict__ out_img)
{
  const int img = blockIdx.x, t = threadIdx.x;
  __shared__ float sd[256][TOPK];
  __shared__ float sv[256];
  __shared__ int   si[256];

  float bv = -1.0f; int bi = 0;
  float bd[TOPK];
  #pragma unroll
  for (int i = 0; i < TOPK; ++i) bd[i] = 0.0f;

  for (int rr = 0; rr < 4; ++rr) {             // ascending rows -> first-max kept
    int row = img * 1024 + rr * 256 + t;
    float best[TOPK];
    #pragma unroll
    for (int i = 0; i < TOPK; ++i) best[i] = 3.4e38f;
    for (int s = 0; s < 2 * NCHUNKS; ++s) {
      const float* p = &partial[((size_t)s * M_ROWS + row) * TOPK];
      #pragma unroll
      for (int i = 0; i < TOPK; ++i) topk_update(p[i], best);
    }
    float nfr = nf[row];
    float dvals[TOPK];
    #pragma unroll
    for (int i = 0; i < TOPK; ++i) dvals[i] = sqrtf(fmaxf(best[i] + nfr, 0.0f));
    out_pix[row] = dvals[0];
    if (dvals[0] > bv) {
      bv = dvals[0]; bi = row;
      #pragma unroll
      for (int i = 0; i < TOPK; ++i) bd[i] = dvals[i];
    }
  }
  sv[t] = bv; si[t] = bi;
  #pragma unroll
  for (int i = 0; i < TOPK; ++i) sd[t][i] = bd[i];
  __syncthreads();
  for (int off = 128; off > 0; off >>= 1) {
    if (t < off) {
      float v2 = sv[t + off]; int i2 = si[t + off];
      if (v2 > sv[t] || (v2 == sv[t] && i2 < si[t])) { sv[t] = v2; si[t] = i2; }
    }
    __syncthreads();
  }
  if (t == 0) {
    int wt = si[0] & 255;
    int b = bptr[0];
    float s0 = sd[wt][0];
    float score = s0;
    if (b > 1) {
      int bb = b < TOPK ? b : TOPK;
      float mx = s0;
      for (int i = 1; i < bb; ++i) mx = fmaxf(mx, sd[wt][i]);
      float den = 0.0f;
      for (int i = 0; i < bb; ++i) den += expf(sd[wt][i] - mx);
      score = s0 * (1.0f - expf(s0 - mx) / den);
    }
    out_img[img] = score;
  }
}

extern "C" void kernel_launch(void* const* d_in, const int* in_sizes, int n_in,
                              void* d_out, int out_size, void* d_ws, size_t ws_size,
                              hipStream_t stream) {
  const float* fv   = (const float*)d_in[0];
  const float* mb   = (const float*)d_in[1];
  const int*   bptr = (const int*)d_in[2];
  float* out = (float*)d_out;

  char* w = (char*)d_ws;
  u8*    fvq     = (u8*)w;                         // 8192*512  = 4194304 B
  u8*    mbq     = (u8*)(w + 4194304);             // 16384*512 = 8388608 B
  float* nf      = (float*)(w + 12582912);         // 32768 B
  float* nm_perm = (float*)(w + 12615680);         // 65536 B
  float* partial = (float*)(w + 12681216);         // 16*8192*9*4 = 4718592 B (end ~17.4 MB)

  hipLaunchKernelGGL(prep_kernel, dim3((M_ROWS + N_ROWS) / 4), dim3(256), 0, stream,
                     fv, mb, (u8*)nullptr, (u8*)nullptr, fvq, mbq, nf, nm_perm);
  hipLaunchKernelGGL(gemm_topk_kernel, dim3(M_ROWS / BM, NCHUNKS), dim3(256), 0, stream,
                     fvq, mbq, nm_perm, partial);
  hipLaunchKernelGGL(scoring_kernel, dim3(8), dim3(256), 0, stream,
                     partial, nf, bptr, out, out + M_ROWS);
}

// Round 9
// 373.407 us; speedup vs baseline: 1.6396x; 1.4395x over previous
//
#include <hip/hip_runtime.h>
#include <hip/hip_bf16.h>
#include <hip/hip_fp8.h>

typedef unsigned short u16;
typedef unsigned char  u8;

#define M_ROWS 8192
#define N_ROWS 16384
#define KDIM   512                  /* fp8: row = 512 B */
#define BM     128
#define BN     128
#define BKB    128                  /* K-bytes staged per kc (packed) */
#define NCHUNKS 8
#define NPER   (N_ROWS / NCHUNKS)   /* 2048 */
#define NT_CNT (NPER / BN)          /* 16 */
#define KC_CNT (KDIM / BKB)         /* 4 */
#define TOPK   9

typedef __attribute__((ext_vector_type(16))) float f32x16;
typedef __attribute__((ext_vector_type(2)))  long  longx2;

__device__ __forceinline__ void gload_lds16(const void* g, void* l) {
  __builtin_amdgcn_global_load_lds(
      (const __attribute__((address_space(1))) void*)g,
      (__attribute__((address_space(3))) void*)l,
      16, 0, 0);
}

__device__ __forceinline__ u8 f2fp8(float x) {
  __hip_fp8_e4m3 q(x);               // OCP e4m3fn on gfx950, RNE+sat
  return (u8)q.__x;
}

__device__ __forceinline__ void topk_update(float v, float best[TOPK]) {
  if (v < best[TOPK - 1]) {
    #pragma unroll
    for (int i = 0; i < TOPK; ++i) {
      float b = best[i];
      best[i] = fminf(b, v);
      v = fmaxf(b, v);
    }
  }
}

// ---- Kernel 1: fp32 -> fp8(e4m3) convert + exact fp32 row norms.
// fp8 rows are written PACKED-BY-H per 128-B kc-tile: phys octet po = h*8 + q
// holds logical octet j = 2q + h  (even octets block, then odd octets block).
// This lets the GEMM stage with width-16 global_load_lds (R8 post-mortem: the
// width-4 staging quadrupled VMEM insts, 228 -> 366 us) AND read fragments as
// ds_read_b128 = two K=16 MFMA fragments per read.
__global__ __launch_bounds__(256) void prep_kernel(
    const float* __restrict__ fv, const float* __restrict__ mb,
    u8* __restrict__ fvq, u8* __restrict__ mbq,
    float* __restrict__ nf, float* __restrict__ nm_perm)
{
  int idx = blockIdx.x * 4 + (threadIdx.x >> 6);   // one wave per row
  int l = threadIdx.x & 63;
  const float* src; u8* dst;
  if (idx < M_ROWS) {
    src = fv + (size_t)idx * KDIM; dst = fvq + (size_t)idx * KDIM;
  } else {
    int r = idx - M_ROWS;
    src = mb + (size_t)r * KDIM; dst = mbq + (size_t)r * KDIM;
  }
  float4 x0 = ((const float4*)src)[2 * l];
  float4 x1 = ((const float4*)src)[2 * l + 1];
  float s = x0.x * x0.x + x0.y * x0.y + x0.z * x0.z + x0.w * x0.w
          + x1.x * x1.x + x1.y * x1.y + x1.z * x1.z + x1.w * x1.w;
  unsigned lo = (unsigned)f2fp8(x0.x) | ((unsigned)f2fp8(x0.y) << 8)
              | ((unsigned)f2fp8(x0.z) << 16) | ((unsigned)f2fp8(x0.w) << 24);
  unsigned hi = (unsigned)f2fp8(x1.x) | ((unsigned)f2fp8(x1.y) << 8)
              | ((unsigned)f2fp8(x1.z) << 16) | ((unsigned)f2fp8(x1.w) << 24);
  uint2 o; o.x = lo; o.y = hi;
  // lane l holds logical octet o = l of the row; packed position:
  int tt = l >> 4;                   // kc-tile (4 tiles of 16 octets)
  int j  = l & 15;                   // logical octet within tile
  int po = ((j & 1) << 3) | (j >> 1);
  ((uint2*)dst)[tt * 16 + po] = o;
  #pragma unroll
  for (int off = 32; off > 0; off >>= 1) s += __shfl_down(s, off, 64);
  if (l == 0) {
    if (idx < M_ROWS) {
      nf[idx] = s;
    } else {
      // 32x32 C/D: within-tile row w5 = (r&3) + 8*(r>>2) + 4*h  ->  [tile][h][r]
      int n  = idx - M_ROWS;
      int ig = n >> 5;
      int w5 = n & 31;
      int h  = (w5 >> 2) & 1;
      int r  = (w5 & 3) | ((w5 >> 3) << 2);
      nm_perm[(ig * 2 + h) * 16 + r] = s;
    }
  }
}

// ---- Kernel 2: fp8 32x32x16 MFMA GEMM, 2x2 wave tile, BKB=128 dbuf ----
// grid (64, 8), block 256. R6 skeleton (plain launch_bounds, dbuf, one barrier
// per kc) with fp8 packed rows: staging = 8 gload_lds16/kc/wave (K=128), frag
// loads = ds_read_b128 feeding TWO MFMAs (kk pair). XOR swizzle: phys 16-B
// chunk p of row r holds packed chunk p^(r&7); frag read chunk (h*4+kp)^(r&7)
// -> 4 lanes/chunk = conflict-free minimum. LDS 64 KB -> 2 blocks/CU, which
// matches the register-dictated 2 waves/SIMD regime (R4-R7 post-mortems).
__global__ __launch_bounds__(256) void gemm_topk_kernel(
    const u8* __restrict__ fvq, const u8* __restrict__ mbq,
    const float* __restrict__ nm_perm, float* __restrict__ partial)
{
  __shared__ __align__(16) u8 As[2][BM * BKB];  // fv tiles, 2 x 16 KB
  __shared__ __align__(16) u8 Bs[2][BN * BKB];  // mb tiles, 2 x 16 KB

  const int t   = threadIdx.x;
  const int l   = t & 63;
  const int w   = t >> 6;
  const int wm  = w & 1;         // m half (cols)
  const int wn  = w >> 1;        // n half (rows)
  const int h   = l >> 5;        // half-wave
  const int c31 = l & 31;
  const int cx7 = c31 & 7;       // frag row & 7

  const int m0    = blockIdx.x * BM;
  const int ncoff = blockIdx.y * NPER;

  // staging: lane l covers row base+(l>>3), phys chunk l&7; source chunk swizzled
  const int srow_lo = l >> 3;                    // 0..7
  const int sc      = ((l & 7) ^ srow_lo) * 16;  // swizzled source byte offset

  float best[2][TOPK];
  float T[2];
  #pragma unroll
  for (int j = 0; j < 2; ++j) {
    T[j] = 3.4e38f;
    #pragma unroll
    for (int i = 0; i < TOPK; ++i) best[j][i] = 3.4e38f;
  }

  // preload tile (nt=0, kc=0) into buffer 0
  #pragma unroll
  for (int g = 0; g < 4; ++g) {
    int row = w * 32 + g * 8 + srow_lo;
    gload_lds16(fvq + (size_t)(m0 + row) * KDIM + sc,
                &As[0][(w * 32 + g * 8) * BKB]);
    gload_lds16(mbq + (size_t)(ncoff + row) * KDIM + sc,
                &Bs[0][(w * 32 + g * 8) * BKB]);
  }

  for (int nt = 0; nt < NT_CNT; ++nt) {
    const int nbase = ncoff + nt * BN;
    f32x16 acc[2][2];
    #pragma unroll
    for (int i = 0; i < 2; ++i)
      #pragma unroll
      for (int j = 0; j < 2; ++j)
        #pragma unroll
        for (int r = 0; r < 16; ++r) acc[i][j][r] = 0.0f;

    for (int kc = 0; kc < KC_CNT; ++kc) {
      const int cur = kc & 1;
      __syncthreads();   // buf[cur] staged (loads issued one kc ago drained here)
      if (kc < KC_CNT - 1) {
        const int kb = (kc + 1) * BKB + sc;
        #pragma unroll
        for (int g = 0; g < 4; ++g) {
          int row = w * 32 + g * 8 + srow_lo;
          gload_lds16(fvq + (size_t)(m0 + row) * KDIM + kb,
                      &As[cur ^ 1][(w * 32 + g * 8) * BKB]);
          gload_lds16(mbq + (size_t)(nbase + row) * KDIM + kb,
                      &Bs[cur ^ 1][(w * 32 + g * 8) * BKB]);
        }
      } else if (nt + 1 < NT_CNT) {
        #pragma unroll
        for (int g = 0; g < 4; ++g) {
          int row = w * 32 + g * 8 + srow_lo;
          gload_lds16(fvq + (size_t)(m0 + row) * KDIM + sc,
                      &As[cur ^ 1][(w * 32 + g * 8) * BKB]);
          gload_lds16(mbq + (size_t)(nbase + BN + row) * KDIM + sc,
                      &Bs[cur ^ 1][(w * 32 + g * 8) * BKB]);
        }
      }
      // compute on buf[cur]: 4 kp steps; each b128 read = 2 MFMA fragments
      const u8* a0 = &As[cur][(wm * 64 + c31) * BKB];
      const u8* a1 = &As[cur][(wm * 64 + 32 + c31) * BKB];
      const u8* b0 = &Bs[cur][(wn * 64 + c31) * BKB];
      const u8* b1 = &Bs[cur][(wn * 64 + 32 + c31) * BKB];
      #pragma unroll
      for (int kp = 0; kp < 4; ++kp) {
        const int ch = ((h * 4 + kp) ^ cx7) * 16;  // swizzled chunk byte offset
        longx2 fvf0 = *(const longx2*)&a0[ch];
        longx2 fvf1 = *(const longx2*)&a1[ch];
        longx2 mbf0 = *(const longx2*)&b0[ch];
        longx2 mbf1 = *(const longx2*)&b1[ch];
        #pragma unroll
        for (int e = 0; e < 2; ++e) {
          acc[0][0] = __builtin_amdgcn_mfma_f32_32x32x16_fp8_fp8(mbf0[e], fvf0[e], acc[0][0], 0, 0, 0);
          acc[0][1] = __builtin_amdgcn_mfma_f32_32x32x16_fp8_fp8(mbf0[e], fvf1[e], acc[0][1], 0, 0, 0);
          acc[1][0] = __builtin_amdgcn_mfma_f32_32x32x16_fp8_fp8(mbf1[e], fvf0[e], acc[1][0], 0, 0, 0);
          acc[1][1] = __builtin_amdgcn_mfma_f32_32x32x16_fp8_fp8(mbf1[e], fvf1[e], acc[1][1], 0, 0, 0);
        }
      }
    }

    // ---- register epilogue: bmin direct from acc; rare branch recomputes ----
    #pragma unroll
    for (int j = 0; j < 2; ++j) {
      float bmin = 3.4e38f;
      #pragma unroll
      for (int i = 0; i < 2; ++i) {
        const float4* np =
            (const float4*)&nm_perm[(((nbase >> 5) + wn * 2 + i) * 2 + h) * 16];
        #pragma unroll
        for (int rr = 0; rr < 4; ++rr) {
          float4 q = np[rr];
          bmin = fminf(bmin, fmaf(-2.0f, acc[i][j][rr * 4 + 0], q.x));
          bmin = fminf(bmin, fmaf(-2.0f, acc[i][j][rr * 4 + 1], q.y));
          bmin = fminf(bmin, fmaf(-2.0f, acc[i][j][rr * 4 + 2], q.z));
          bmin = fminf(bmin, fmaf(-2.0f, acc[i][j][rr * 4 + 3], q.w));
        }
      }
      if (bmin < T[j]) {
        #pragma unroll
        for (int i = 0; i < 2; ++i) {
          const float4* np =
              (const float4*)&nm_perm[(((nbase >> 5) + wn * 2 + i) * 2 + h) * 16];
          #pragma unroll
          for (int rr = 0; rr < 4; ++rr) {
            float4 q = np[rr];
            topk_update(fmaf(-2.0f, acc[i][j][rr * 4 + 0], q.x), best[j]);
            topk_update(fmaf(-2.0f, acc[i][j][rr * 4 + 1], q.y), best[j]);
            topk_update(fmaf(-2.0f, acc[i][j][rr * 4 + 2], q.z), best[j]);
            topk_update(fmaf(-2.0f, acc[i][j][rr * 4 + 3], q.w), best[j]);
          }
        }
      }
      float th = best[j][TOPK - 1];
      T[j] = fminf(th, __shfl_xor(th, 32, 64));
    }
  }

  // merge the h-pair sharing each m-col (snapshot partner list, then insert)
  #pragma unroll
  for (int j = 0; j < 2; ++j) {
    float tmp[TOPK];
    #pragma unroll
    for (int s = 0; s < TOPK; ++s) tmp[s] = __shfl_xor(best[j][s], 32, 64);
    #pragma unroll
    for (int s = 0; s < TOPK; ++s) topk_update(tmp[s], best[j]);
  }
  // 16 lists per row: (blockIdx.y, wn); h=0 writes 5, h=1 writes 4
  #pragma unroll
  for (int j = 0; j < 2; ++j) {
    int m = m0 + wm * 64 + j * 32 + c31;
    size_t base = ((size_t)(blockIdx.y * 2 + wn) * M_ROWS + m) * TOPK;
    if (h == 0) {
      #pragma unroll
      for (int s = 0; s < 5; ++s) partial[base + s] = best[j][s];
    } else {
      #pragma unroll
      for (int s = 5; s < TOPK; ++s) partial[base + s] = best[j][s];
    }
  }
}

// ---- Kernel 3 (fused merge+img): one block per image; merge 16 lists/row,
//      sqrt, pixel scores, per-image first-max argmax, softmax image score.
__global__ __launch_bounds__(256) void scoring_kernel(
    const float* __restrict__ partial, const float* __restrict__ nf,
    const int* __restrict__ bptr, float* __restrict__ out_pix,
    float* __restrict__ out_img)
{
  const int img = blockIdx.x, t = threadIdx.x;
  __shared__ float sd[256][TOPK];
  __shared__ float sv[256];
  __shared__ int   si[256];

  float bv = -1.0f; int bi = 0;
  float bd[TOPK];
  #pragma unroll
  for (int i = 0; i < TOPK; ++i) bd[i] = 0.0f;

  for (int rr = 0; rr < 4; ++rr) {             // ascending rows -> first-max kept
    int row = img * 1024 + rr * 256 + t;
    float best[TOPK];
    #pragma unroll
    for (int i = 0; i < TOPK; ++i) best[i] = 3.4e38f;
    for (int s = 0; s < 2 * NCHUNKS; ++s) {
      const float* p = &partial[((size_t)s * M_ROWS + row) * TOPK];
      #pragma unroll
      for (int i = 0; i < TOPK; ++i) topk_update(p[i], best);
    }
    float nfr = nf[row];
    float dvals[TOPK];
    #pragma unroll
    for (int i = 0; i < TOPK; ++i) dvals[i] = sqrtf(fmaxf(best[i] + nfr, 0.0f));
    out_pix[row] = dvals[0];
    if (dvals[0] > bv) {
      bv = dvals[0]; bi = row;
      #pragma unroll
      for (int i = 0; i < TOPK; ++i) bd[i] = dvals[i];
    }
  }
  sv[t] = bv; si[t] = bi;
  #pragma unroll
  for (int i = 0; i < TOPK; ++i) sd[t][i] = bd[i];
  __syncthreads();
  for (int off = 128; off > 0; off >>= 1) {
    if (t < off) {
      float v2 = sv[t + off]; int i2 = si[t + off];
      if (v2 > sv[t] || (v2 == sv[t] && i2 < si[t])) { sv[t] = v2; si[t] = i2; }
    }
    __syncthreads();
  }
  if (t == 0) {
    int wt = si[0] & 255;
    int b = bptr[0];
    float s0 = sd[wt][0];
    float score = s0;
    if (b > 1) {
      int bb = b < TOPK ? b : TOPK;
      float mx = s0;
      for (int i = 1; i < bb; ++i) mx = fmaxf(mx, sd[wt][i]);
      float den = 0.0f;
      for (int i = 0; i < bb; ++i) den += expf(sd[wt][i] - mx);
      score = s0 * (1.0f - expf(s0 - mx) / den);
    }
    out_img[img] = score;
  }
}

extern "C" void kernel_launch(void* const* d_in, const int* in_sizes, int n_in,
                              void* d_out, int out_size, void* d_ws, size_t ws_size,
                              hipStream_t stream) {
  const float* fv   = (const float*)d_in[0];
  const float* mb   = (const float*)d_in[1];
  const int*   bptr = (const int*)d_in[2];
  float* out = (float*)d_out;

  char* w = (char*)d_ws;
  u8*    fvq     = (u8*)w;                         // 8192*512  = 4194304 B
  u8*    mbq     = (u8*)(w + 4194304);             // 16384*512 = 8388608 B
  float* nf      = (float*)(w + 12582912);         // 32768 B
  float* nm_perm = (float*)(w + 12615680);         // 65536 B
  float* partial = (float*)(w + 12681216);         // 16*8192*9*4 = 4718592 B (end ~17.4 MB)

  hipLaunchKernelGGL(prep_kernel, dim3((M_ROWS + N_ROWS) / 4), dim3(256), 0, stream,
                     fv, mb, fvq, mbq, nf, nm_perm);
  hipLaunchKernelGGL(gemm_topk_kernel, dim3(M_ROWS / BM, NCHUNKS), dim3(256), 0, stream,
                     fvq, mbq, nm_perm, partial);
  hipLaunchKernelGGL(scoring_kernel, dim3(8), dim3(256), 0, stream,
                     partial, nf, bptr, out, out + M_ROWS);
}